// Round 3
// baseline (2095.003 us; speedup 1.0000x reference)
//
#include <hip/hip_runtime.h>
#include <hip/hip_fp16.h>
#include <stdint.h>

// ---------------------------------------------------------------------------
// SeqAE: enc LSTM (3->200, T=800, B=256) -> maxpool(T) -> dec LSTM (200->3)
// R3: 1 WG/batch, 256 threads (4 waves, 1/SIMD). Thread t (t<200) owns hidden
// unit t: all 4 gate rows (t, t+200, t+400, t+600) = 400 f16-pair VGPRs.
// Per step: 25 uniform ds_read_b128 of h per wave (100/CU, was 312 in R2 --
// the measured LDS-pipe bottleneck), 400 dot2/thread, thread-local gate
// nonlinearities + c/h update + maxpool, ds_write_b16 of h, ONE barrier
// (double-buffered h). Decoder fused (bitwise fixed-point early exit).
// ---------------------------------------------------------------------------

typedef _Float16 half2_t __attribute__((ext_vector_type(2)));

__device__ __forceinline__ float fdot2f(uint32_t hp, uint32_t wp, float acc) {
#if __has_builtin(__builtin_amdgcn_fdot2)
  return __builtin_amdgcn_fdot2(__builtin_bit_cast(half2_t, hp),
                                __builtin_bit_cast(half2_t, wp), acc, false);
#else
  half2_t a = __builtin_bit_cast(half2_t, hp);
  half2_t b = __builtin_bit_cast(half2_t, wp);
  return acc + (float)a[0] * (float)b[0] + (float)a[1] * (float)b[1];
#endif
}

__device__ __forceinline__ float hsig(float z) {
  return fminf(fmaxf(__builtin_fmaf(0.2f, z, 0.5f), 0.f), 1.f);
}

// tanh(x) = 1 - 2/(1+e^{2x});  e^{2x} = exp2(x * 2*log2(e))
__device__ __forceinline__ float tanh_fast(float v) {
  float e = __builtin_amdgcn_exp2f(v * 2.885390081777927f);
  return 1.f - 2.f * __builtin_amdgcn_rcpf(e + 1.f);
}

// --- pack Whh (800x200 f32, row-major) into f16 pairs, layout wpk[pair][row]
__global__ void prep_kernel(const float* __restrict__ whh,
                            uint32_t* __restrict__ wpk) {
  int idx = blockIdx.x * 256 + threadIdx.x;      // 100 pairs * 800 rows
  if (idx >= 80000) return;
  int p = idx / 800;
  int j = idx - p * 800;
  float a = whh[j * 200 + 2 * p];
  float b = whh[j * 200 + 2 * p + 1];
  __half2 v = __floats2half2_rn(a, b);
  wpk[idx] = __builtin_bit_cast(uint32_t, v);
}

// --- fused encoder + maxpool + decoder: grid 256 (batch), 256 threads
__global__ __launch_bounds__(256, 1)
void enc_kernel(const float* __restrict__ x,       // (256,3,800)
                const float* __restrict__ wih,     // (800,3)
                const float* __restrict__ bih,     // (800)
                const float* __restrict__ bhh,     // (800)
                const uint32_t* __restrict__ wpk,  // (100,800) f16 pairs
                const float* __restrict__ dwih,    // (12,200)
                const float* __restrict__ dbih,    // (12)
                const float* __restrict__ dbhh,    // (12)
                const float* __restrict__ dwhh,    // (12,3)
                float* __restrict__ out)           // (256,3,800)
{
  const int b = blockIdx.x;
  const int t = threadIdx.x;

  __shared__ alignas(16) float xs[3200];        // [800][4]; reused as dec hist
  __shared__ alignas(16) __half hh[2][208];     // double-buffered h (f16)
  __shared__ float pooled[200];
  __shared__ float pre12s[12];
  __shared__ int s_tc;

  // stage x: xs[tt*4 + f] = x[b, f, tt]; 4th component zero (b128 writes)
  {
    const float* xb = x + (size_t)b * 2400;
    float4* X4 = (float4*)xs;
    for (int tt = t; tt < 800; tt += 256) {
      float4 v;
      v.x = xb[tt];
      v.y = xb[800 + tt];
      v.z = xb[1600 + tt];
      v.w = 0.f;
      X4[tt] = v;
    }
  }
  if (t < 208) { hh[0][t] = __float2half(0.f); }

  const bool worker = t < 200;
  uint32_t w[400];          // gate g (i,f,g,o), pair p: w[g*100+p] = Whh[t+200g, 2p..2p+1]
  float bias[4] = {0, 0, 0, 0};
  float wi[12];             // wi[g*3 + k]
#pragma unroll
  for (int j = 0; j < 12; ++j) wi[j] = 0.f;
  if (worker) {
#pragma unroll
    for (int g = 0; g < 4; ++g) {
      const int row = t + 200 * g;
#pragma unroll
      for (int p = 0; p < 100; ++p) w[g * 100 + p] = wpk[p * 800 + row];  // coalesced
      bias[g] = bih[row] + bhh[row];
      wi[g * 3 + 0] = wih[row * 3 + 0];
      wi[g * 3 + 1] = wih[row * 3 + 1];
      wi[g * 3 + 2] = wih[row * 3 + 2];
    }
  }
  float c_state = 0.f;
  float maxh = -INFINITY;
  __syncthreads();

  int cur = 0;
  for (int step = 0; step < 800; ++step) {
    if (worker) {
      float acc[8];         // 2 accumulators per gate (even/odd q)
#pragma unroll
      for (int j = 0; j < 8; ++j) acc[j] = 0.f;
      const uint4* H4 = (const uint4*)hh[cur];
#pragma unroll
      for (int q = 0; q < 25; ++q) {
        uint4 Hv = H4[q];                       // uniform broadcast b128
        const int d = q & 1;
#pragma unroll
        for (int g = 0; g < 4; ++g) {
          float a = acc[2 * g + d];
          a = fdot2f(Hv.x, w[g * 100 + 4 * q + 0], a);
          a = fdot2f(Hv.y, w[g * 100 + 4 * q + 1], a);
          a = fdot2f(Hv.z, w[g * 100 + 4 * q + 2], a);
          a = fdot2f(Hv.w, w[g * 100 + 4 * q + 3], a);
          acc[2 * g + d] = a;
        }
      }
      float4 xv = ((const float4*)xs)[step];    // uniform broadcast b128
      float gte[4];
#pragma unroll
      for (int g = 0; g < 4; ++g) {
        float v = acc[2 * g] + acc[2 * g + 1] + bias[g];
        v = __builtin_fmaf(wi[g * 3 + 0], xv.x, v);
        v = __builtin_fmaf(wi[g * 3 + 1], xv.y, v);
        v = __builtin_fmaf(wi[g * 3 + 2], xv.z, v);
        gte[g] = v;
      }
      float i_ = hsig(gte[0]), f_ = hsig(gte[1]), o_ = hsig(gte[3]);
      float g_ = tanh_fast(gte[2]);
      c_state = __builtin_fmaf(f_, c_state, i_ * g_);
      float h_ = o_ * tanh_fast(c_state);
      maxh = fmaxf(maxh, h_);
      hh[cur ^ 1][t] = __float2half(h_);        // ds_write_b16
    }
    __syncthreads();
    cur ^= 1;
  }

  // ---- maxpool -> decoder constant input pre12 ----
  if (worker) pooled[t] = maxh;
  __syncthreads();
  if (t < 12) {
    float s = dbih[t] + dbhh[t];
    const float* wr = dwih + t * 200;
#pragma unroll 8
    for (int u = 0; u < 200; ++u) s = __builtin_fmaf(pooled[u], wr[u], s);
    pre12s[t] = s;
  }
  __syncthreads();

  // ---- decoder: lanes 0..2 run the 6-dim recurrence redundantly; feature f
  //      history goes to xs[step*4 + f]. Bitwise fixed-point early exit.
  if (t < 3) {
    float pre[12];
#pragma unroll
    for (int j = 0; j < 12; ++j) pre[j] = pre12s[j];
    float W[36];
#pragma unroll
    for (int j = 0; j < 36; ++j) W[j] = dwhh[j];

    float h0 = 0, h1 = 0, h2 = 0, c0 = 0, c1 = 0, c2 = 0;
    int tc = 800;
    for (int step = 0; step < 800; ++step) {
      float g[12];
#pragma unroll
      for (int j = 0; j < 12; ++j) {
        float v = pre[j];
        v = __builtin_fmaf(W[j * 3 + 0], h0, v);
        v = __builtin_fmaf(W[j * 3 + 1], h1, v);
        v = __builtin_fmaf(W[j * 3 + 2], h2, v);
        g[j] = v;
      }
      float nc0 = hsig(g[3]) * c0 + hsig(g[0]) * tanh_fast(g[6]);
      float nc1 = hsig(g[4]) * c1 + hsig(g[1]) * tanh_fast(g[7]);
      float nc2 = hsig(g[5]) * c2 + hsig(g[2]) * tanh_fast(g[8]);
      float nh0 = hsig(g[9])  * tanh_fast(nc0);
      float nh1 = hsig(g[10]) * tanh_fast(nc1);
      float nh2 = hsig(g[11]) * tanh_fast(nc2);
      bool same = (nh0 == h0) && (nh1 == h1) && (nh2 == h2) &&
                  (nc0 == c0) && (nc1 == c1) && (nc2 == c2);
      float mine = (t == 0) ? nh0 : ((t == 1) ? nh1 : nh2);
      xs[step * 4 + t] = mine;
      h0 = nh0; h1 = nh1; h2 = nh2; c0 = nc0; c1 = nc1; c2 = nc2;
      if (same) { tc = step + 1; break; }       // exact fixed point
    }
    if (t == 0) s_tc = tc;
  }
  __syncthreads();

  // ---- coalesced writeback: out[b, f, tt] = hist[f][min(tt, tc-1)] ----
  {
    const int tcv = s_tc, tc1 = tcv - 1;
    float* ob = out + (size_t)b * 2400;
    for (int tt = t; tt < 800; tt += 256) {
      int idx = (tt < tcv) ? tt : tc1;
      ob[tt]        = xs[idx * 4 + 0];
      ob[800 + tt]  = xs[idx * 4 + 1];
      ob[1600 + tt] = xs[idx * 4 + 2];
    }
  }
}

extern "C" void kernel_launch(void* const* d_in, const int* in_sizes, int n_in,
                              void* d_out, int out_size, void* d_ws, size_t ws_size,
                              hipStream_t stream)
{
  const float* x    = (const float*)d_in[0];
  const float* wih  = (const float*)d_in[1];
  const float* whh  = (const float*)d_in[2];
  const float* bih  = (const float*)d_in[3];
  const float* bhh  = (const float*)d_in[4];
  const float* dwih = (const float*)d_in[5];
  const float* dwhh = (const float*)d_in[6];
  const float* dbih = (const float*)d_in[7];
  const float* dbhh = (const float*)d_in[8];
  float* out = (float*)d_out;

  uint32_t* wpk = (uint32_t*)d_ws;   // 320000 B

  hipLaunchKernelGGL(prep_kernel, dim3(313), dim3(256), 0, stream, whh, wpk);
  hipLaunchKernelGGL(enc_kernel, dim3(256), dim3(256), 0, stream,
                     x, wih, bih, bhh, wpk, dwih, dbih, dbhh, dwhh, out);
}

// Round 4
// 1322.942 us; speedup vs baseline: 1.5836x; 1.5836x over previous
//
#include <hip/hip_runtime.h>
#include <hip/hip_fp16.h>
#include <stdint.h>

// ---------------------------------------------------------------------------
// SeqAE: enc LSTM (3->200, T=800, B=256) -> maxpool(T) -> dec LSTM (200->3)
// R4: 1 WG/batch, 512 threads (8 waves, 2/SIMD). Split-K: waves 0-3 (A) own
// h-pairs 0..49, waves 4-7 (B) own pairs 50..99. Thread owns unit u's 4 gate
// rows x its 50 pairs = 200 weight VGPRs, pinned via asm (R1-R3: compiler
// remat/sank unpinned arrays -> L2 refetch every step). h broadcast via ONE
// ds_read_b128 + 50 readlane -> SGPR operands of v_dot2_f32_f16 (LDS pipe was
// the R2 bottleneck at 12cy/uniform-b128). B sends 4 partials to A via LDS;
// A does gates/c/h/maxpool thread-locally. 2 barriers/step.
// ---------------------------------------------------------------------------

typedef _Float16 half2_t __attribute__((ext_vector_type(2)));

__device__ __forceinline__ float fdot2f(uint32_t hp, uint32_t wp, float acc) {
#if __has_builtin(__builtin_amdgcn_fdot2)
  return __builtin_amdgcn_fdot2(__builtin_bit_cast(half2_t, hp),
                                __builtin_bit_cast(half2_t, wp), acc, false);
#else
  half2_t a = __builtin_bit_cast(half2_t, hp);
  half2_t b = __builtin_bit_cast(half2_t, wp);
  return acc + (float)a[0] * (float)b[0] + (float)a[1] * (float)b[1];
#endif
}

__device__ __forceinline__ float hsig(float z) {
  return fminf(fmaxf(__builtin_fmaf(0.2f, z, 0.5f), 0.f), 1.f);
}

__device__ __forceinline__ float tanh_fast(float v) {
  float e = __builtin_amdgcn_exp2f(v * 2.885390081777927f);
  return 1.f - 2.f * __builtin_amdgcn_rcpf(e + 1.f);
}

// --- pack Whh (800x200 f32, row-major) into f16 pairs, layout wpk[pair][row]
__global__ void prep_kernel(const float* __restrict__ whh,
                            uint32_t* __restrict__ wpk) {
  int idx = blockIdx.x * 256 + threadIdx.x;      // 100 pairs * 800 rows
  if (idx >= 80000) return;
  int p = idx / 800;
  int j = idx - p * 800;
  float a = whh[j * 200 + 2 * p];
  float b = whh[j * 200 + 2 * p + 1];
  __half2 v = __floats2half2_rn(a, b);
  wpk[idx] = __builtin_bit_cast(uint32_t, v);
}

// --- fused encoder + maxpool + decoder: grid 256 (batch), 512 threads
__global__ __launch_bounds__(512, 1)
void enc_kernel(const float* __restrict__ x,       // (256,3,800)
                const float* __restrict__ wih,     // (800,3)
                const float* __restrict__ bih,     // (800)
                const float* __restrict__ bhh,     // (800)
                const uint32_t* __restrict__ wpk,  // (100,800) f16 pairs
                const float* __restrict__ dwih,    // (12,200)
                const float* __restrict__ dbih,    // (12)
                const float* __restrict__ dbhh,    // (12)
                const float* __restrict__ dwhh,    // (12,3)
                float* __restrict__ out)           // (256,3,800)
{
  const int b = blockIdx.x;
  const int t = threadIdx.x;
  const int lane = t & 63;

  __shared__ alignas(16) __half xs[3200];        // [800][4] f16 (x0,x1,x2,0)
  __shared__ alignas(16) __half hh[2][224];      // double-buffered h (f16)
  __shared__ alignas(16) float part[256][4];     // B->A partial sums
  __shared__ float hist[3200];                   // decoder history [800][4]
  __shared__ float pooled[200];
  __shared__ float pre12s[12];
  __shared__ int s_tc;

  // stage x as f16 quads: xs[tt*4+f]
  {
    const float* xb = x + (size_t)b * 2400;
    for (int tt = t; tt < 800; tt += 512) {
      __half2 h01 = __floats2half2_rn(xb[tt], xb[800 + tt]);
      __half2 h23 = __floats2half2_rn(xb[1600 + tt], 0.f);
      uint2 v;
      v.x = __builtin_bit_cast(uint32_t, h01);
      v.y = __builtin_bit_cast(uint32_t, h23);
      ((uint2*)xs)[tt] = v;
    }
  }
  if (t < 224) hh[0][t] = __float2half(0.f);

  const bool isB = t >= 256;           // waves 4-7: K-half 1
  const int u = isB ? (t - 256) : t;   // unit 0..255 (200..255 dummy)
  const int poff = isB ? 50 : 0;

  // weights: w[g*50 + p] = Whh[row(u,g), 2*(poff+p) .. +1], rows clamped
  uint32_t w[200];
  {
#pragma unroll
    for (int g = 0; g < 4; ++g) {
      int row = u + 200 * g; if (row > 799) row = 799;   // dummy-safe
      const uint32_t* src = wpk + (size_t)poff * 800 + row;
#pragma unroll
      for (int p = 0; p < 50; ++p) w[g * 50 + p] = src[p * 800];
    }
  }
#pragma unroll
  for (int p = 0; p < 200; ++p) asm volatile("" : "+v"(w[p]));  // pin resident

  // A-only epilogue constants (packed f16 Wih + bias)
  uint32_t wi2[8];
  float bias[4] = {0, 0, 0, 0};
  if (!isB) {
#pragma unroll
    for (int g = 0; g < 4; ++g) {
      int row = u + 200 * g; if (row > 799) row = 799;
      __half2 ha = __floats2half2_rn(wih[row * 3 + 0], wih[row * 3 + 1]);
      __half2 hb = __floats2half2_rn(wih[row * 3 + 2], 0.f);
      wi2[g * 2 + 0] = __builtin_bit_cast(uint32_t, ha);
      wi2[g * 2 + 1] = __builtin_bit_cast(uint32_t, hb);
      bias[g] = bih[row] + bhh[row];
    }
  } else {
#pragma unroll
    for (int j = 0; j < 8; ++j) wi2[j] = 0;
  }

  float c_state = 0.f;
  float maxh = -INFINITY;
  __syncthreads();

  int cur = 0;
  for (int step = 0; step < 800; ++step) {
    // 1) each wave reads ITS 200B h-half: lanes 0..12 cover 50 dwords
    const uint4* hbase = (const uint4*)(hh[cur] + (isB ? 100 : 0));
    uint4 hv = hbase[lane < 13 ? lane : 12];

    // 2) 50 readlane -> SGPR h-pairs, 4 dots each (one per gate)
    float acc[8];
#pragma unroll
    for (int j = 0; j < 8; ++j) acc[j] = 0.f;
#pragma unroll
    for (int p = 0; p < 50; ++p) {
      const int ln = p >> 2, d = p & 3;
      uint32_t comp = (d == 0) ? hv.x : (d == 1) ? hv.y : (d == 2) ? hv.z : hv.w;
      uint32_t hp = __builtin_amdgcn_readlane(comp, ln);   // wave-uniform SGPR
#pragma unroll
      for (int g = 0; g < 4; ++g)
        acc[2 * g + (p & 1)] = fdot2f(hp, w[g * 50 + p], acc[2 * g + (p & 1)]);
    }

    if (isB) {      // 3) B sends its 4 partial sums to A
      float4 pv;
      pv.x = acc[0] + acc[1];
      pv.y = acc[2] + acc[3];
      pv.z = acc[4] + acc[5];
      pv.w = acc[6] + acc[7];
      *(float4*)part[u] = pv;
    }
    __syncthreads();

    if (!isB && t < 200) {   // 4) A: combine, gates, c/h update, maxpool
      float4 pv = *(const float4*)part[u];
      uint2 xv = ((const uint2*)xs)[step];
      float gte[4];
      const float pb[4] = {pv.x, pv.y, pv.z, pv.w};
#pragma unroll
      for (int g = 0; g < 4; ++g) {
        float v = acc[2 * g] + acc[2 * g + 1] + pb[g] + bias[g];
        v = fdot2f(xv.x, wi2[g * 2 + 0], v);
        v = fdot2f(xv.y, wi2[g * 2 + 1], v);
        gte[g] = v;
      }
      float i_ = hsig(gte[0]), f_ = hsig(gte[1]), o_ = hsig(gte[3]);
      float g_ = tanh_fast(gte[2]);
      c_state = __builtin_fmaf(f_, c_state, i_ * g_);
      float h_ = o_ * tanh_fast(c_state);
      maxh = fmaxf(maxh, h_);
      hh[cur ^ 1][u] = __float2half(h_);
    }
    __syncthreads();
    cur ^= 1;
  }

  // ---- maxpool -> decoder constant input pre12 ----
  if (t < 200) pooled[t] = maxh;
  __syncthreads();
  if (t < 12) {
    float s = dbih[t] + dbhh[t];
    const float* wr = dwih + t * 200;
#pragma unroll 8
    for (int uu = 0; uu < 200; ++uu) s = __builtin_fmaf(pooled[uu], wr[uu], s);
    pre12s[t] = s;
  }
  __syncthreads();

  // ---- decoder: lanes 0..2, 6-dim recurrence, bitwise fixed-point exit ----
  if (t < 3) {
    float pre[12];
#pragma unroll
    for (int j = 0; j < 12; ++j) pre[j] = pre12s[j];
    float W[36];
#pragma unroll
    for (int j = 0; j < 36; ++j) W[j] = dwhh[j];

    float h0 = 0, h1 = 0, h2 = 0, c0 = 0, c1 = 0, c2 = 0;
    int tc = 800;
    for (int step = 0; step < 800; ++step) {
      float g[12];
#pragma unroll
      for (int j = 0; j < 12; ++j) {
        float v = pre[j];
        v = __builtin_fmaf(W[j * 3 + 0], h0, v);
        v = __builtin_fmaf(W[j * 3 + 1], h1, v);
        v = __builtin_fmaf(W[j * 3 + 2], h2, v);
        g[j] = v;
      }
      float nc0 = hsig(g[3]) * c0 + hsig(g[0]) * tanh_fast(g[6]);
      float nc1 = hsig(g[4]) * c1 + hsig(g[1]) * tanh_fast(g[7]);
      float nc2 = hsig(g[5]) * c2 + hsig(g[2]) * tanh_fast(g[8]);
      float nh0 = hsig(g[9])  * tanh_fast(nc0);
      float nh1 = hsig(g[10]) * tanh_fast(nc1);
      float nh2 = hsig(g[11]) * tanh_fast(nc2);
      bool same = (nh0 == h0) && (nh1 == h1) && (nh2 == h2) &&
                  (nc0 == c0) && (nc1 == c1) && (nc2 == c2);
      float mine = (t == 0) ? nh0 : ((t == 1) ? nh1 : nh2);
      hist[step * 4 + t] = mine;
      h0 = nh0; h1 = nh1; h2 = nh2; c0 = nc0; c1 = nc1; c2 = nc2;
      if (same) { tc = step + 1; break; }       // exact fixed point
    }
    if (t == 0) s_tc = tc;
  }
  __syncthreads();

  // ---- coalesced writeback: out[b, f, tt] = hist[f][min(tt, tc-1)] ----
  {
    const int tcv = s_tc, tc1 = tcv - 1;
    float* ob = out + (size_t)b * 2400;
    for (int tt = t; tt < 800; tt += 512) {
      int idx = (tt < tcv) ? tt : tc1;
      ob[tt]        = hist[idx * 4 + 0];
      ob[800 + tt]  = hist[idx * 4 + 1];
      ob[1600 + tt] = hist[idx * 4 + 2];
    }
  }
}

extern "C" void kernel_launch(void* const* d_in, const int* in_sizes, int n_in,
                              void* d_out, int out_size, void* d_ws, size_t ws_size,
                              hipStream_t stream)
{
  const float* x    = (const float*)d_in[0];
  const float* wih  = (const float*)d_in[1];
  const float* whh  = (const float*)d_in[2];
  const float* bih  = (const float*)d_in[3];
  const float* bhh  = (const float*)d_in[4];
  const float* dwih = (const float*)d_in[5];
  const float* dwhh = (const float*)d_in[6];
  const float* dbih = (const float*)d_in[7];
  const float* dbhh = (const float*)d_in[8];
  float* out = (float*)d_out;

  uint32_t* wpk = (uint32_t*)d_ws;   // 320000 B

  hipLaunchKernelGGL(prep_kernel, dim3(313), dim3(256), 0, stream, whh, wpk);
  hipLaunchKernelGGL(enc_kernel, dim3(256), dim3(512), 0, stream,
                     x, wih, bih, bhh, wpk, dwih, dbih, dbhh, dwhh, out);
}